// Round 1
// baseline (187.633 us; speedup 1.0000x reference)
//
#include <hip/hip_runtime.h>

#define CMIN -1024.0f
#define CMAX 1016.0f

__device__ __forceinline__ float clampv(float x) {
    return fminf(fmaxf(x, CMIN), CMAX);
}

// ---------------------------------------------------------------------------
// Pass 1: per-channel sum of clamped DC coefficients of c.
// c layout: [2, 256, 256, 8, 8] -> DC of block b is flat index b*64.
// 131072 DC values total; 65536 per channel. Block = 256 threads, each block
// lies entirely within one channel (65536 % 256 == 0).
// ---------------------------------------------------------------------------
__global__ void __launch_bounds__(256)
dc_sum_kernel(const float* __restrict__ c, float* __restrict__ ws,
              int dc_per_ch) {
    int t = blockIdx.x * blockDim.x + threadIdx.x;
    float v = clampv(c[(size_t)t * 64]);

    // wave-64 shuffle reduction
    #pragma unroll
    for (int off = 32; off > 0; off >>= 1)
        v += __shfl_down(v, off, 64);

    __shared__ float smem[4];  // 256 threads = 4 waves
    int lane = threadIdx.x & 63;
    int wave = threadIdx.x >> 6;
    if (lane == 0) smem[wave] = v;
    __syncthreads();
    if (threadIdx.x == 0) {
        float s = smem[0] + smem[1] + smem[2] + smem[3];
        int ch = (blockIdx.x * 256 < dc_per_ch) ? 0 : 1;
        atomicAdd(&ws[ch], s);
    }
}

// ---------------------------------------------------------------------------
// Pass 2a: y = clamp(clamp(y) * 1.9)   (fully elementwise, float4)
// ---------------------------------------------------------------------------
__global__ void __launch_bounds__(256)
y_kernel(const float4* __restrict__ y, float4* __restrict__ out, int nvec) {
    int i = blockIdx.x * blockDim.x + threadIdx.x;
    if (i >= nvec) return;
    float4 v = y[i];
    v.x = clampv(clampv(v.x) * 1.9f);
    v.y = clampv(clampv(v.y) * 1.9f);
    v.z = clampv(clampv(v.z) * 1.9f);
    v.w = clampv(clampv(v.w) * 1.9f);
    out[i] = v;
}

// ---------------------------------------------------------------------------
// Pass 2b: c contrast. cv = clamp(c); r = cv*1.9; DC (.x of every 16th
// float4) additionally gets -0.9*dc_mean[ch]; then clamp.
// ---------------------------------------------------------------------------
__global__ void __launch_bounds__(256)
c_kernel(const float4* __restrict__ c, float4* __restrict__ out,
         const float* __restrict__ ws, int nvec, int half_nvec,
         float inv_count) {
    int i = blockIdx.x * blockDim.x + threadIdx.x;
    if (i >= nvec) return;
    float4 v = c[i];
    float4 r;
    r.x = clampv(v.x) * 1.9f;
    r.y = clampv(v.y) * 1.9f;
    r.z = clampv(v.z) * 1.9f;
    r.w = clampv(v.w) * 1.9f;
    if ((i & 15) == 0) {
        int ch = (i < half_nvec) ? 0 : 1;
        float dc_mean = ws[ch] * inv_count;
        r.x += -0.9f * dc_mean;
    }
    r.x = clampv(r.x);
    r.y = clampv(r.y);
    r.z = clampv(r.z);
    r.w = clampv(r.w);
    out[i] = r;
}

extern "C" void kernel_launch(void* const* d_in, const int* in_sizes, int n_in,
                              void* d_out, int out_size, void* d_ws, size_t ws_size,
                              hipStream_t stream) {
    const float* y = (const float*)d_in[0];
    const float* c = (const float*)d_in[1];
    float* out = (float*)d_out;

    const int yN = in_sizes[0];             // 16777216
    const int cN = in_sizes[1];             // 8388608
    float* out_y = out;
    float* out_c = out + yN;

    float* ws = (float*)d_ws;               // ws[0], ws[1] = per-channel DC sums

    // zero the accumulators (d_ws is re-poisoned to 0xAA before every launch)
    hipMemsetAsync(ws, 0, 2 * sizeof(float), stream);

    // Pass 1: DC reduction over c
    const int dc_count = cN / 64;           // 131072
    const int dc_per_ch = dc_count / 2;     // 65536
    dc_sum_kernel<<<dc_count / 256, 256, 0, stream>>>(c, ws, dc_per_ch);

    // Pass 2: elementwise
    const int ynvec = yN / 4;               // 4194304
    y_kernel<<<(ynvec + 255) / 256, 256, 0, stream>>>(
        (const float4*)y, (float4*)out_y, ynvec);

    const int cnvec = cN / 4;               // 2097152
    const float inv_count = 1.0f / (float)dc_per_ch;
    c_kernel<<<(cnvec + 255) / 256, 256, 0, stream>>>(
        (const float4*)c, (float4*)out_c, ws, cnvec, cnvec / 2, inv_count);
}

// Round 2
// 183.747 us; speedup vs baseline: 1.0211x; 1.0211x over previous
//
#include <hip/hip_runtime.h>

#define CMIN -1024.0f
#define CMAX 1016.0f

__device__ __forceinline__ float clampv(float x) {
    return fminf(fmaxf(x, CMIN), CMAX);
}

// ---------------------------------------------------------------------------
// Pass 1: per-channel sum of clamped DC coefficients of c.
// c layout: [2, 256, 256, 8, 8] -> DC of block b is flat index b*64.
// 131072 DC values total; 65536 per channel; 512 workgroups of 256, each
// wholly inside one channel.
// ---------------------------------------------------------------------------
__global__ void __launch_bounds__(256)
dc_sum_kernel(const float* __restrict__ c, float* __restrict__ ws,
              int dc_per_ch) {
    int t = blockIdx.x * blockDim.x + threadIdx.x;
    float v = clampv(c[(size_t)t * 64]);

    // wave-64 shuffle reduction
    #pragma unroll
    for (int off = 32; off > 0; off >>= 1)
        v += __shfl_down(v, off, 64);

    __shared__ float smem[4];  // 256 threads = 4 waves
    int lane = threadIdx.x & 63;
    int wave = threadIdx.x >> 6;
    if (lane == 0) smem[wave] = v;
    __syncthreads();
    if (threadIdx.x == 0) {
        float s = smem[0] + smem[1] + smem[2] + smem[3];
        int ch = (blockIdx.x * 256 < dc_per_ch) ? 0 : 1;
        atomicAdd(&ws[ch], s);
    }
}

// ---------------------------------------------------------------------------
// Pass 2 (fused): elementwise over y then c, one grid.
//   i <  ynvec           : out[i] = clamp(clamp(y[i]) * 1.9)
//   i >= ynvec (c range) : cv = clamp(c); r = cv*1.9; DC element (.x of every
//                          16th float4) += -0.9*dc_mean[ch]; clamp; store.
// ---------------------------------------------------------------------------
__global__ void __launch_bounds__(256)
fused_elementwise(const float4* __restrict__ y, const float4* __restrict__ c,
                  float4* __restrict__ out, const float* __restrict__ ws,
                  int ynvec, int total_nvec, int c_half_nvec,
                  float inv_count) {
    int i = blockIdx.x * blockDim.x + threadIdx.x;
    if (i >= total_nvec) return;

    if (i < ynvec) {
        float4 v = y[i];
        v.x = clampv(clampv(v.x) * 1.9f);
        v.y = clampv(clampv(v.y) * 1.9f);
        v.z = clampv(clampv(v.z) * 1.9f);
        v.w = clampv(clampv(v.w) * 1.9f);
        out[i] = v;
    } else {
        int ci = i - ynvec;
        float4 v = c[ci];
        float4 r;
        r.x = clampv(v.x) * 1.9f;
        r.y = clampv(v.y) * 1.9f;
        r.z = clampv(v.z) * 1.9f;
        r.w = clampv(v.w) * 1.9f;
        if ((ci & 15) == 0) {
            int ch = (ci < c_half_nvec) ? 0 : 1;
            r.x += -0.9f * (ws[ch] * inv_count);
        }
        r.x = clampv(r.x);
        r.y = clampv(r.y);
        r.z = clampv(r.z);
        r.w = clampv(r.w);
        out[i] = r;
    }
}

extern "C" void kernel_launch(void* const* d_in, const int* in_sizes, int n_in,
                              void* d_out, int out_size, void* d_ws, size_t ws_size,
                              hipStream_t stream) {
    const float* y = (const float*)d_in[0];
    const float* c = (const float*)d_in[1];
    float* out = (float*)d_out;

    const int yN = in_sizes[0];             // 16777216
    const int cN = in_sizes[1];             // 8388608

    float* ws = (float*)d_ws;               // ws[0], ws[1] = per-channel DC sums

    // zero the accumulators (d_ws is re-poisoned to 0xAA before every launch)
    hipMemsetAsync(ws, 0, 2 * sizeof(float), stream);

    // Pass 1: DC reduction over c
    const int dc_count = cN / 64;           // 131072
    const int dc_per_ch = dc_count / 2;     // 65536
    dc_sum_kernel<<<dc_count / 256, 256, 0, stream>>>(c, ws, dc_per_ch);

    // Pass 2: fused elementwise over y and c
    const int ynvec = yN / 4;               // 4194304
    const int cnvec = cN / 4;               // 2097152
    const int total_nvec = ynvec + cnvec;   // 6291456
    const float inv_count = 1.0f / (float)dc_per_ch;
    fused_elementwise<<<(total_nvec + 255) / 256, 256, 0, stream>>>(
        (const float4*)y, (const float4*)c, (float4*)out, ws,
        ynvec, total_nvec, cnvec / 2, inv_count);
}